// Round 9
// baseline (594.742 us; speedup 1.0000x reference)
//
#include <hip/hip_runtime.h>

#define PER  149796
#define NN   1048573          // 1 + 7*PER
#define HDIM 64
#define EDIM 32
#define NIOU 192
#define STG  96               // staged child rows per chunk

typedef _Float16 f16;
typedef _Float16 f16x8 __attribute__((ext_vector_type(8)));
typedef _Float16 f16x4 __attribute__((ext_vector_type(4)));
typedef _Float16 f16x2 __attribute__((ext_vector_type(2)));
typedef float    f32x4 __attribute__((ext_vector_type(4)));

typedef __attribute__((address_space(1))) const unsigned gu32;
typedef __attribute__((address_space(3))) unsigned lu32;

__device__ __forceinline__ float sigf(float x){ return 1.0f/(1.0f+__expf(-x)); }
__device__ __forceinline__ float tanh_f(float x){
  float ax = fabsf(x);
  float e  = __expf(-2.0f*ax);
  float t  = (1.0f - e)/(1.0f + e);
  return x < 0.0f ? -t : t;
}

// ================= CSR build =================
__global__ __launch_bounds__(256) void countAll_kernel(const int* __restrict__ parent,
                                                       int* __restrict__ cnt){
  int idx = blockIdx.x*256 + threadIdx.x;
  if (idx >= 6*PER) return;
  atomicAdd(&cnt[parent[1 + PER + idx]], 1);
}

// cnt[0] never counted (level-1 scatter skipped): treat as PER in scans.
// (cnt garbage at leaf indices only corrupts off[] beyond 1+6*PER, which the
//  leaf dispatch never reads — it uses leafLevel=1.)
__device__ __forceinline__ int cnt_at(const int* cnt, int idx){
  return (idx == 0) ? PER : cnt[idx];
}

__global__ __launch_bounds__(256) void scan1_kernel(const int* __restrict__ cnt, int* __restrict__ bsum){
  __shared__ int sc[256];
  int b = blockIdx.x, t = threadIdx.x;
  int base = b*1024 + t*4;
  int s = 0;
  #pragma unroll
  for (int e=0;e<4;e++){ int idx=base+e; if (idx<NN) s += cnt_at(cnt, idx); }
  sc[t]=s; __syncthreads();
  for (int d=128; d>0; d>>=1){ if (t<d) sc[t]+=sc[t+d]; __syncthreads(); }
  if (t==0) bsum[b]=sc[0];
}

__global__ __launch_bounds__(1024) void scan2_kernel(const int* __restrict__ bsum, int* __restrict__ bbase){
  __shared__ int sc[1024];
  int t=threadIdx.x;
  sc[t]=bsum[t]; __syncthreads();
  for (int d=1; d<1024; d<<=1){
    int v = (t>=d)? sc[t-d] : 0; __syncthreads();
    sc[t]+=v; __syncthreads();
  }
  bbase[t] = (t==0)?0:sc[t-1];
}

__global__ __launch_bounds__(256) void scan3_kernel(const int* __restrict__ cnt, const int* __restrict__ bbase,
                                                    int* __restrict__ off, int* __restrict__ cursor){
  __shared__ int sc[256];
  int b=blockIdx.x, t=threadIdx.x;
  int base=b*1024+t*4;
  int e0 = (base  <NN)?cnt_at(cnt,base  ):0;
  int e1 = (base+1<NN)?cnt_at(cnt,base+1):0;
  int e2 = (base+2<NN)?cnt_at(cnt,base+2):0;
  int e3 = (base+3<NN)?cnt_at(cnt,base+3):0;
  int tsum=e0+e1+e2+e3;
  sc[t]=tsum; __syncthreads();
  for (int d=1; d<256; d<<=1){
    int v=(t>=d)?sc[t-d]:0; __syncthreads();
    sc[t]+=v; __syncthreads();
  }
  int x = bbase[b] + ((t==0)?0:sc[t-1]);
  if (base  <NN){ off[base  ]=x;          cursor[base  ]=x; }
  if (base+1<NN){ off[base+1]=x+e0;       cursor[base+1]=x+e0; }
  if (base+2<NN){ off[base+2]=x+e0+e1;    cursor[base+2]=x+e0+e1; }
  if (base+3<NN){ off[base+3]=x+e0+e1+e2; cursor[base+3]=x+e0+e1+e2; }
}

__global__ __launch_bounds__(256) void scatterAll_kernel(const int* __restrict__ parent,
    const int* __restrict__ tok, int* __restrict__ cursor,
    int* __restrict__ childpos, int* __restrict__ ptok){
  int idx = blockIdx.x*256 + threadIdx.x;
  if (idx >= 6*PER) return;
  int g = 1 + PER + idx;
  int jp = parent[g];
  int pos = atomicAdd(&cursor[jp], 1);
  childpos[g] = pos;
  ptok[pos] = tok[jp];
}

// ================= tables + MFMA packs (fused) =================
// B-frag order for mfma_f32_16x16x32_f16 (verified R4): lane L: n=t*16+(L&15), k=s*32+(L>>4)*8+j
__global__ __launch_bounds__(256) void tablepack_kernel(
    const float* __restrict__ emb, const float* __restrict__ Wiou, const float* __restrict__ biou,
    const float* __restrict__ Wf, const float* __restrict__ bf,
    const float* __restrict__ Uf, const float* __restrict__ Uiou,
    float* __restrict__ embWiou, float* __restrict__ embWf,
    f16* __restrict__ Bfp, f16* __restrict__ Biop)
{
  if (blockIdx.x < 1024){
    int v = blockIdx.x;
    int m = threadIdx.x;
    const float* x = emb + (size_t)v*EDIM;
    if (m < NIOU){
      float a = biou[m];
      #pragma unroll
      for (int e=0;e<EDIM;e++) a += Wiou[m*EDIM+e]*x[e];
      embWiou[(size_t)v*NIOU + m] = a;
    } else {
      int mm = m - NIOU;
      float a = bf[mm];
      #pragma unroll
      for (int e=0;e<EDIM;e++) a += Wf[mm*EDIM+e]*x[e];
      embWf[(size_t)v*HDIM + mm] = a;
    }
  } else {
    for (int i = threadIdx.x; i < 2*4*64*8; i += 256){
      int j = i & 7, L = (i>>3)&63, st = i>>9;
      int t = st & 3, s = st >> 2;
      int k = s*32 + (L>>4)*8 + j;
      int n = t*16 + (L&15);
      Bfp[i] = (f16)Uf[n*HDIM + k];
    }
    for (int i = threadIdx.x; i < 2*12*64*8; i += 256){
      int j = i & 7, L = (i>>3)&63, st = i>>9;
      int t = st % 12, s = st / 12;
      int k = s*32 + (L>>4)*8 + j;
      int n = t*16 + (L&15);
      Biop[i] = (f16)Uiou[n*HDIM + k];
    }
  }
}

// ================= fused node kernel (also handles leaf level) =================
// phase1: async-stage contiguous child rows into LDS, segmented sum from LDS
//         (leafLevel: skipped entirely, sums are zero)
// phase2: MFMA Hsum @ Uiou^T + activation epilogue (h,c in regs)
// phase3: h -> LDS -> A-frags -> MFMA Uf -> write {h,fc} f16x2
// LDS: stage (24.6 KB) aliased with Ah+FAf (18 KB) — stage fully consumed
// before Ah/FAf written; chunk-loop trip count is block-uniform so the final
// in-loop __syncthreads orders the reuse.
__global__ __launch_bounds__(256) void node_fused(
    const int* __restrict__ tok, const int* __restrict__ off,
    const int* __restrict__ childpos, const int* __restrict__ ptok,
    const float* __restrict__ embWiou, const float* __restrict__ embWf,
    const f16* __restrict__ Biopack, const f16* __restrict__ Ufpack,
    const f16x2* __restrict__ HFin, f16x2* __restrict__ HFout,
    int poff, int relbase, int outbase, int identityOut, int leafLevel)
{
  __shared__ __align__(16) char smem[STG*HDIM*4];   // 24576 B
  f16x2* stage = (f16x2*)smem;
  f16*   Ah    = (f16*)smem;                        // 64*72*2 = 9216
  f16*   FAf   = (f16*)(smem + 9216);               // 64*68*2 = 8704
  int lane = threadIdx.x & 63;
  int wv   = __builtin_amdgcn_readfirstlane(threadIdx.x >> 6);
  int p0   = wv*16;
  int j0b  = blockIdx.x*64;
  int j0   = j0b + p0;

  float hs[16], fa[16];
  #pragma unroll
  for (int i=0;i<16;i++){ hs[i]=0.f; fa[i]=0.f; }

  if (!leafLevel){
    int ei = j0b + 64; if (ei > PER) ei = PER;
    int S = off[poff + j0b] - relbase;
    int E = off[poff + ei]  - relbase;
    int sB[17];
    #pragma unroll
    for (int i=0;i<=16;i++){
      int jj = j0 + i; if (jj > PER) jj = PER;
      sB[i] = off[poff + jj] - relbase;
    }
    const unsigned* HFinU = (const unsigned*)HFin;
    for (int cb = S; cb < E; cb += STG){
      int n = E - cb; if (n > STG) n = STG;
      for (int r = wv; r < n; r += 4){
        gu32* gp = (gu32*)(HFinU + (size_t)(cb+r)*HDIM) + lane;
        __builtin_amdgcn_global_load_lds(gp, (lu32*)&stage[r*HDIM], 4, 0, 0);
      }
      __syncthreads();
      int lim = cb + n;
      #pragma unroll
      for (int i=0;i<16;i++){
        int lo = sB[i]   > cb  ? sB[i]   : cb;
        int hi = sB[i+1] < lim ? sB[i+1] : lim;
        for (int p=lo; p<hi; ++p){
          f16x2 v = stage[(p-cb)*HDIM + lane];
          hs[i] += (float)v.x; fa[i] += (float)v.y;
        }
      }
      __syncthreads();
    }
  }
  // stage consumed (or never used) — safe to write aliased Ah/FAf
  #pragma unroll
  for (int i=0;i<16;i++){
    Ah[(p0+i)*72 + lane]  = (f16)hs[i];
    FAf[(p0+i)*68 + lane] = (f16)fa[i];
  }
  __syncthreads();
  // ---- phase 2: iou MFMA + epilogue
  int q = lane>>4, c16 = lane&15;
  f16x8 A0 = *(const f16x8*)(Ah + (p0+c16)*72 + q*8);
  f16x8 A1 = *(const f16x8*)(Ah + (p0+c16)*72 + 32 + q*8);
  const f16x8* Bp = (const f16x8*)Biopack;
  f32x4 acc[12];
  #pragma unroll
  for (int nt=0;nt<12;nt++) acc[nt] = (f32x4){0.f,0.f,0.f,0.f};
  #pragma unroll
  for (int nt=0;nt<12;nt++){
    f16x8 B0 = Bp[nt*64 + lane];
    f16x8 B1 = Bp[(12+nt)*64 + lane];
    acc[nt] = __builtin_amdgcn_mfma_f32_16x16x32_f16(A0, B0, acc[nt], 0,0,0);
    acc[nt] = __builtin_amdgcn_mfma_f32_16x16x32_f16(A1, B1, acc[nt], 0,0,0);
  }
  int tok0 = identityOut ? tok[0] : 0;
  float cc[4][4];
  f16   hh[4][4];
  int   opos_[4]; int wt_[4]; bool ok_[4];
  #pragma unroll
  for (int r=0;r<4;r++){
    int j = j0 + q*4 + r;
    bool ok = j < PER;
    int jl = ok ? j : PER-1;
    int g = poff + jl;
    int tk = tok[g];
    const float* tr = embWiou + (size_t)tk*NIOU;
    int opg = identityOut ? (outbase + jl) : childpos[g];
    int op  = opg - outbase;
    opos_[r]=op; ok_[r]=ok;
    wt_[r] = identityOut ? tok0 : ptok[opg];
    int prow = p0 + q*4 + r;
    #pragma unroll
    for (int nt=0;nt<4;nt++){
      int col = nt*16 + c16;
      float ai = acc[nt][r]   + tr[col];
      float ao = acc[nt+4][r] + tr[64+col];
      float au = acc[nt+8][r] + tr[128+col];
      float fav = (float)FAf[prow*68 + col];
      float c = sigf(ai)*tanh_f(au) + fav;
      float h = sigf(ao)*tanh_f(c);
      cc[r][nt] = c;
      hh[r][nt] = (f16)h;
    }
  }
  __syncthreads();
  // ---- phase 3: h -> Ah, Uf MFMA, write {h,fc}
  #pragma unroll
  for (int r=0;r<4;r++)
    #pragma unroll
    for (int nt=0;nt<4;nt++)
      Ah[(p0+q*4+r)*72 + nt*16 + c16] = hh[r][nt];
  __syncthreads();
  f16x8 H0 = *(const f16x8*)(Ah + (p0+c16)*72 + q*8);
  f16x8 H1 = *(const f16x8*)(Ah + (p0+c16)*72 + 32 + q*8);
  const f16x8* Up = (const f16x8*)Ufpack;
  f32x4 g4[4];
  #pragma unroll
  for (int nt=0;nt<4;nt++) g4[nt] = (f32x4){0.f,0.f,0.f,0.f};
  #pragma unroll
  for (int nt=0;nt<4;nt++){
    f16x8 B0 = Up[nt*64 + lane];
    f16x8 B1 = Up[(4+nt)*64 + lane];
    g4[nt] = __builtin_amdgcn_mfma_f32_16x16x32_f16(H0, B0, g4[nt], 0,0,0);
    g4[nt] = __builtin_amdgcn_mfma_f32_16x16x32_f16(H1, B1, g4[nt], 0,0,0);
  }
  #pragma unroll
  for (int r=0;r<4;r++){
    if (!ok_[r]) continue;
    const float* wr = embWf + (size_t)wt_[r]*HDIM;
    int op = opos_[r];
    #pragma unroll
    for (int nt=0;nt<4;nt++){
      int col = nt*16 + c16;
      float v = sigf(g4[nt][r] + wr[col]) * cc[r][nt];
      f16x2 o; o.x = hh[r][nt]; o.y = (f16)v;
      HFout[(size_t)op*HDIM + col] = o;
    }
  }
}

// ================= root =================
__global__ __launch_bounds__(256) void rootred_kernel(
    const f16x2* __restrict__ HFin, float* __restrict__ rootacc)
{
  int t = blockIdx.x*blockDim.x + threadIdx.x;
  int m = t & 63;
  int j0 = t >> 6;
  int jstep = (gridDim.x*blockDim.x) >> 6;
  float af=0.f, ah=0.f;
  for (int j=j0; j<PER; j+=jstep){
    f16x2 v = HFin[(size_t)j*HDIM + m];
    ah += (float)v.x;
    af += (float)v.y;
  }
  __shared__ float red[256];
  red[threadIdx.x]=af; __syncthreads();
  if (threadIdx.x < 64) atomicAdd(&rootacc[m],    red[m]+red[64+m]+red[128+m]+red[192+m]);
  __syncthreads();
  red[threadIdx.x]=ah; __syncthreads();
  if (threadIdx.x < 64) atomicAdd(&rootacc[64+m], red[m]+red[64+m]+red[128+m]+red[192+m]);
}

__global__ void rootnode_kernel(
    const int* __restrict__ tok, const float* __restrict__ emb,
    const float* __restrict__ Wiou, const float* __restrict__ biou, const float* __restrict__ Uiou,
    const float* __restrict__ rootacc, float* __restrict__ out)
{
  int m = threadIdx.x;
  if (m >= HDIM) return;
  int t = tok[0];
  float ai=biou[m], ao=biou[HDIM+m], au=biou[2*HDIM+m];
  for (int e=0;e<EDIM;e++){
    float xe = emb[(size_t)t*EDIM+e];
    ai += Wiou[(size_t)m*EDIM+e]*xe;
    ao += Wiou[(size_t)(HDIM+m)*EDIM+e]*xe;
    au += Wiou[(size_t)(2*HDIM+m)*EDIM+e]*xe;
  }
  for (int k=0;k<HDIM;k++){
    float hv = rootacc[64+k];
    ai += Uiou[(size_t)m*HDIM+k]*hv;
    ao += Uiou[(size_t)(HDIM+m)*HDIM+k]*hv;
    au += Uiou[(size_t)(2*HDIM+m)*HDIM+k]*hv;
  }
  float c = sigf(ai)*tanh_f(au) + rootacc[m];
  out[m] = sigf(ao)*tanh_f(c);
}

// ================= launch =================
static inline char* alignup(char* p){
  uintptr_t u = (uintptr_t)p;
  u = (u + 255) & ~(uintptr_t)255;
  return (char*)u;
}

extern "C" void kernel_launch(void* const* d_in, const int* in_sizes, int n_in,
                              void* d_out, int out_size, void* d_ws, size_t ws_size,
                              hipStream_t stream)
{
  const int*   tok    = (const int*)d_in[0];
  const int*   parent = (const int*)d_in[1];
  const float* emb    = (const float*)d_in[4];
  const float* Wiou   = (const float*)d_in[5];
  const float* biou   = (const float*)d_in[6];
  const float* Uiou   = (const float*)d_in[7];
  const float* Wf     = (const float*)d_in[8];
  const float* bf     = (const float*)d_in[9];
  const float* Uf     = (const float*)d_in[10];
  float* out = (float*)d_out;

  char* w = (char*)d_ws;
  f16x2* HFA     = (f16x2*)w;  w = alignup(w + (size_t)PER*HDIM*sizeof(f16x2));
  f16x2* HFB     = (f16x2*)w;  w = alignup(w + (size_t)PER*HDIM*sizeof(f16x2));
  int*   cnt     = (int*)w;    w = alignup(w + (size_t)NN*sizeof(int));
  int*   off     = (int*)w;    w = alignup(w + (size_t)NN*sizeof(int));
  int*   cursor  = (int*)w;    w = alignup(w + (size_t)NN*sizeof(int));
  int*   childpos= (int*)w;    w = alignup(w + (size_t)NN*sizeof(int));
  int*   ptok    = (int*)w;    w = alignup(w + (size_t)NN*sizeof(int));
  int*   bsum    = (int*)w;    w = alignup(w + 1024*sizeof(int));
  int*   bbase   = (int*)w;    w = alignup(w + 1024*sizeof(int));
  float* embWiou = (float*)w;  w = alignup(w + 1024*NIOU*sizeof(float));
  float* embWf   = (float*)w;  w = alignup(w + 1024*HDIM*sizeof(float));
  float* rootacc = (float*)w;  w = alignup(w + 128*sizeof(float));
  f16*   Ufpack  = (f16*)w;    w = alignup(w + 2*4*64*8*sizeof(f16));
  f16*   Biopack = (f16*)w;    w = alignup(w + 2*12*64*8*sizeof(f16));

  const int gALL = (6*PER + 255)/256;     // 3511

  hipMemsetAsync(cnt, 0, (size_t)(1 + 6*PER)*sizeof(int), stream);
  hipMemsetAsync(rootacc, 0, 128*sizeof(float), stream);

  countAll_kernel  <<<gALL, 256, 0, stream>>>(parent, cnt);
  scan1_kernel     <<<1024, 256, 0, stream>>>(cnt, bsum);
  scan2_kernel     <<<1, 1024, 0, stream>>>(bsum, bbase);
  scan3_kernel     <<<1024, 256, 0, stream>>>(cnt, bbase, off, cursor);
  scatterAll_kernel<<<gALL, 256, 0, stream>>>(parent, tok, cursor, childpos, ptok);
  tablepack_kernel <<<1025, 256, 0, stream>>>(emb, Wiou, biou, Wf, bf, Uf, Uiou,
                                              embWiou, embWf, Ufpack, Biopack);

  // levels d=7 (leaves, no children) down to d=1
  f16x2* bufs[2] = {HFA, HFB};
  int outIdx = 0;
  f16x2* last = HFA;
  for (int d=7; d>=1; --d){
    int poff = 1 + (d-1)*PER;
    f16x2* in  = bufs[1-outIdx];
    f16x2* ou  = bufs[outIdx];
    node_fused<<<(PER + 63)/64, 256, 0, stream>>>(tok, off, childpos, ptok,
                                                  embWiou, embWf, Biopack, Ufpack,
                                                  in, ou,
                                                  poff, d*PER, (d-1)*PER,
                                                  (d==1) ? 1 : 0, (d==7) ? 1 : 0);
    last = ou;
    outIdx ^= 1;
  }

  // root: children are level-1 nodes at rel positions [0,PER)
  rootred_kernel<<<256, 256, 0, stream>>>(last, rootacc);
  rootnode_kernel<<<1, 64, 0, stream>>>(tok, emb, Wiou, biou, Uiou, rootacc, out);
}

// Round 10
// 553.638 us; speedup vs baseline: 1.0742x; 1.0742x over previous
//
#include <hip/hip_runtime.h>

#define PER  149796
#define NN   1048573          // 1 + 7*PER
#define HDIM 64
#define EDIM 32
#define NIOU 192
#define STG  96               // staged child rows per chunk

typedef _Float16 f16;
typedef _Float16 f16x8 __attribute__((ext_vector_type(8)));
typedef _Float16 f16x4 __attribute__((ext_vector_type(4)));
typedef _Float16 f16x2 __attribute__((ext_vector_type(2)));
typedef float    f32x4 __attribute__((ext_vector_type(4)));

typedef __attribute__((address_space(1))) const unsigned gu32;
typedef __attribute__((address_space(3))) unsigned lu32;

__device__ __forceinline__ float sigf(float x){ return 1.0f/(1.0f+__expf(-x)); }
__device__ __forceinline__ float tanh_f(float x){
  float ax = fabsf(x);
  float e  = __expf(-2.0f*ax);
  float t  = (1.0f - e)/(1.0f + e);
  return x < 0.0f ? -t : t;
}

// ================= CSR build =================
// children of levels 2..7 (g in [1+PER, NN)); parents levels 1..6
__global__ __launch_bounds__(256) void countAll_kernel(const int* __restrict__ parent,
                                                       int* __restrict__ cnt){
  int idx = blockIdx.x*256 + threadIdx.x;
  if (idx >= 6*PER) return;
  atomicAdd(&cnt[parent[1 + PER + idx]], 1);
}

// NOTE: cnt beyond 1+6*PER (leaf region) is never memset — garbage there only
// corrupts off[] entries >= leaf start, which are never read.
__global__ __launch_bounds__(256) void scan1_kernel(const int* __restrict__ cnt, int* __restrict__ bsum){
  __shared__ int sc[256];
  int b = blockIdx.x, t = threadIdx.x;
  int base = b*1024 + t*4;
  int s = 0;
  #pragma unroll
  for (int e=0;e<4;e++){ int idx=base+e; if (idx<NN) s += cnt[idx]; }
  sc[t]=s; __syncthreads();
  for (int d=128; d>0; d>>=1){ if (t<d) sc[t]+=sc[t+d]; __syncthreads(); }
  if (t==0) bsum[b]=sc[0];
}

__global__ __launch_bounds__(1024) void scan2_kernel(const int* __restrict__ bsum, int* __restrict__ bbase){
  __shared__ int sc[1024];
  int t=threadIdx.x;
  sc[t]=bsum[t]; __syncthreads();
  for (int d=1; d<1024; d<<=1){
    int v = (t>=d)? sc[t-d] : 0; __syncthreads();
    sc[t]+=v; __syncthreads();
  }
  bbase[t] = (t==0)?0:sc[t-1];
}

__global__ __launch_bounds__(256) void scan3_kernel(const int* __restrict__ cnt, const int* __restrict__ bbase,
                                                    int* __restrict__ off, int* __restrict__ cursor){
  __shared__ int sc[256];
  int b=blockIdx.x, t=threadIdx.x;
  int base=b*1024+t*4;
  int e0 = (base  <NN)?cnt[base  ]:0;
  int e1 = (base+1<NN)?cnt[base+1]:0;
  int e2 = (base+2<NN)?cnt[base+2]:0;
  int e3 = (base+3<NN)?cnt[base+3]:0;
  int tsum=e0+e1+e2+e3;
  sc[t]=tsum; __syncthreads();
  for (int d=1; d<256; d<<=1){
    int v=(t>=d)?sc[t-d]:0; __syncthreads();
    sc[t]+=v; __syncthreads();
  }
  int x = bbase[b] + ((t==0)?0:sc[t-1]);
  if (base  <NN){ off[base  ]=x;          cursor[base  ]=x; }
  if (base+1<NN){ off[base+1]=x+e0;       cursor[base+1]=x+e0; }
  if (base+2<NN){ off[base+2]=x+e0+e1;    cursor[base+2]=x+e0+e1; }
  if (base+3<NN){ off[base+3]=x+e0+e1+e2; cursor[base+3]=x+e0+e1+e2; }
}

// scatter: childrow[pos] = child's level-local node index
__global__ __launch_bounds__(256) void scatterAll_kernel(const int* __restrict__ parent,
    int* __restrict__ cursor, int* __restrict__ childrow){
  int idx = blockIdx.x*256 + threadIdx.x;
  if (idx >= 6*PER) return;
  int g = 1 + PER + idx;
  int jp = parent[g];
  int pos = atomicAdd(&cursor[jp], 1);
  childrow[pos] = idx % PER;     // level-local row of child g
}

// ================= tables + MFMA packs (fused) =================
// B-frag order for mfma_f32_16x16x32_f16 (verified R4): lane L: n=t*16+(L&15), k=s*32+(L>>4)*8+j
__global__ __launch_bounds__(256) void tablepack_kernel(
    const float* __restrict__ emb, const float* __restrict__ Wiou, const float* __restrict__ biou,
    const float* __restrict__ Wf, const float* __restrict__ bf,
    const float* __restrict__ Uf, const float* __restrict__ Uiou,
    float* __restrict__ embWiou, float* __restrict__ embWf,
    f16* __restrict__ Bfp, f16* __restrict__ Biop)
{
  if (blockIdx.x < 1024){
    int v = blockIdx.x;
    int m = threadIdx.x;
    const float* x = emb + (size_t)v*EDIM;
    if (m < NIOU){
      float a = biou[m];
      #pragma unroll
      for (int e=0;e<EDIM;e++) a += Wiou[m*EDIM+e]*x[e];
      embWiou[(size_t)v*NIOU + m] = a;
    } else {
      int mm = m - NIOU;
      float a = bf[mm];
      #pragma unroll
      for (int e=0;e<EDIM;e++) a += Wf[mm*EDIM+e]*x[e];
      embWf[(size_t)v*HDIM + mm] = a;
    }
  } else {
    for (int i = threadIdx.x; i < 2*4*64*8; i += 256){
      int j = i & 7, L = (i>>3)&63, st = i>>9;
      int t = st & 3, s = st >> 2;
      int k = s*32 + (L>>4)*8 + j;
      int n = t*16 + (L&15);
      Bfp[i] = (f16)Uf[n*HDIM + k];
    }
    for (int i = threadIdx.x; i < 2*12*64*8; i += 256){
      int j = i & 7, L = (i>>3)&63, st = i>>9;
      int t = st % 12, s = st / 12;
      int k = s*32 + (L>>4)*8 + j;
      int n = t*16 + (L&15);
      Biop[i] = (f16)Uiou[n*HDIM + k];
    }
  }
}

// ================= fused node kernel (also handles leaf level) =================
// Storage is NODE-ORDER per level. Gather uses CSR: segment bounds off[],
// source rows childrow[pos]. Writes are contiguous streaming.
// phase1: async-stage child rows (random rows via childrow) into LDS, segmented sum
// phase2: MFMA Hsum @ Uiou^T + activation epilogue
// phase3: h -> LDS -> A-frags -> MFMA Uf -> write {h,fc} f16x2 at own node row
// LDS: stage (24.6 KB) aliased with Ah+FAf (17.9 KB); stage fully consumed
// before Ah/FAf written (block-uniform chunk count + in-loop __syncthreads).
__global__ __launch_bounds__(256) void node_fused(
    const int* __restrict__ tok, const int* __restrict__ parent,
    const int* __restrict__ off, const int* __restrict__ childrow,
    const float* __restrict__ embWiou, const float* __restrict__ embWf,
    const f16* __restrict__ Biopack, const f16* __restrict__ Ufpack,
    const f16x2* __restrict__ HFin, f16x2* __restrict__ HFout,
    int poff, int leafLevel)
{
  __shared__ __align__(16) char smem[STG*HDIM*4];   // 24576 B
  f16x2* stage = (f16x2*)smem;
  f16*   Ah    = (f16*)smem;                        // 64*72*2 = 9216
  f16*   FAf   = (f16*)(smem + 9216);               // 64*68*2 = 8704
  int lane = threadIdx.x & 63;
  int wv   = __builtin_amdgcn_readfirstlane(threadIdx.x >> 6);
  int p0   = wv*16;
  int j0b  = blockIdx.x*64;
  int j0   = j0b + p0;

  float hs[16], fa[16];
  #pragma unroll
  for (int i=0;i<16;i++){ hs[i]=0.f; fa[i]=0.f; }

  if (!leafLevel){
    int ei = j0b + 64; if (ei > PER) ei = PER;
    int S = off[poff + j0b];
    int E = off[poff + ei];
    int sB[17];
    #pragma unroll
    for (int i=0;i<=16;i++){
      int jj = j0 + i; if (jj > PER) jj = PER;
      sB[i] = off[poff + jj];
    }
    const unsigned* HFinU = (const unsigned*)HFin;
    for (int cb = S; cb < E; cb += STG){
      int n = E - cb; if (n > STG) n = STG;
      for (int r = wv; r < n; r += 4){
        int srow = childrow[cb + r];                 // wave-uniform
        gu32* gp = (gu32*)(HFinU + (size_t)srow*HDIM) + lane;
        __builtin_amdgcn_global_load_lds(gp, (lu32*)&stage[r*HDIM], 4, 0, 0);
      }
      __syncthreads();
      int lim = cb + n;
      #pragma unroll
      for (int i=0;i<16;i++){
        int lo = sB[i]   > cb  ? sB[i]   : cb;
        int hi = sB[i+1] < lim ? sB[i+1] : lim;
        for (int p=lo; p<hi; ++p){
          f16x2 v = stage[(p-cb)*HDIM + lane];
          hs[i] += (float)v.x; fa[i] += (float)v.y;
        }
      }
      __syncthreads();
    }
  }
  // stage consumed (or never used) — safe to write aliased Ah/FAf
  #pragma unroll
  for (int i=0;i<16;i++){
    Ah[(p0+i)*72 + lane]  = (f16)hs[i];
    FAf[(p0+i)*68 + lane] = (f16)fa[i];
  }
  __syncthreads();
  // ---- phase 2: iou MFMA + epilogue
  int q = lane>>4, c16 = lane&15;
  f16x8 A0 = *(const f16x8*)(Ah + (p0+c16)*72 + q*8);
  f16x8 A1 = *(const f16x8*)(Ah + (p0+c16)*72 + 32 + q*8);
  const f16x8* Bp = (const f16x8*)Biopack;
  f32x4 acc[12];
  #pragma unroll
  for (int nt=0;nt<12;nt++) acc[nt] = (f32x4){0.f,0.f,0.f,0.f};
  #pragma unroll
  for (int nt=0;nt<12;nt++){
    f16x8 B0 = Bp[nt*64 + lane];
    f16x8 B1 = Bp[(12+nt)*64 + lane];
    acc[nt] = __builtin_amdgcn_mfma_f32_16x16x32_f16(A0, B0, acc[nt], 0,0,0);
    acc[nt] = __builtin_amdgcn_mfma_f32_16x16x32_f16(A1, B1, acc[nt], 0,0,0);
  }
  float cc[4][4];
  f16   hh[4][4];
  int   wt_[4]; bool ok_[4];
  #pragma unroll
  for (int r=0;r<4;r++){
    int j = j0 + q*4 + r;
    bool ok = j < PER;
    int jl = ok ? j : PER-1;
    int g = poff + jl;
    int tk = tok[g];
    const float* tr = embWiou + (size_t)tk*NIOU;
    wt_[r] = tok[parent[g]];         // parent's token for the Uf part
    ok_[r] = ok;
    int prow = p0 + q*4 + r;
    #pragma unroll
    for (int nt=0;nt<4;nt++){
      int col = nt*16 + c16;
      float ai = acc[nt][r]   + tr[col];
      float ao = acc[nt+4][r] + tr[64+col];
      float au = acc[nt+8][r] + tr[128+col];
      float fav = (float)FAf[prow*68 + col];
      float c = sigf(ai)*tanh_f(au) + fav;
      float h = sigf(ao)*tanh_f(c);
      cc[r][nt] = c;
      hh[r][nt] = (f16)h;
    }
  }
  __syncthreads();
  // ---- phase 3: h -> Ah, Uf MFMA, write {h,fc} at own node row (contiguous)
  #pragma unroll
  for (int r=0;r<4;r++)
    #pragma unroll
    for (int nt=0;nt<4;nt++)
      Ah[(p0+q*4+r)*72 + nt*16 + c16] = hh[r][nt];
  __syncthreads();
  f16x8 H0 = *(const f16x8*)(Ah + (p0+c16)*72 + q*8);
  f16x8 H1 = *(const f16x8*)(Ah + (p0+c16)*72 + 32 + q*8);
  const f16x8* Up = (const f16x8*)Ufpack;
  f32x4 g4[4];
  #pragma unroll
  for (int nt=0;nt<4;nt++) g4[nt] = (f32x4){0.f,0.f,0.f,0.f};
  #pragma unroll
  for (int nt=0;nt<4;nt++){
    f16x8 B0 = Up[nt*64 + lane];
    f16x8 B1 = Up[(4+nt)*64 + lane];
    g4[nt] = __builtin_amdgcn_mfma_f32_16x16x32_f16(H0, B0, g4[nt], 0,0,0);
    g4[nt] = __builtin_amdgcn_mfma_f32_16x16x32_f16(H1, B1, g4[nt], 0,0,0);
  }
  #pragma unroll
  for (int r=0;r<4;r++){
    if (!ok_[r]) continue;
    const float* wr = embWf + (size_t)wt_[r]*HDIM;
    int j = j0 + q*4 + r;
    #pragma unroll
    for (int nt=0;nt<4;nt++){
      int col = nt*16 + c16;
      float v = sigf(g4[nt][r] + wr[col]) * cc[r][nt];
      f16x2 o; o.x = hh[r][nt]; o.y = (f16)v;
      HFout[(size_t)j*HDIM + col] = o;
    }
  }
}

// ================= root =================
__global__ __launch_bounds__(256) void rootred_kernel(
    const f16x2* __restrict__ HFin, float* __restrict__ rootacc)
{
  int t = blockIdx.x*blockDim.x + threadIdx.x;
  int m = t & 63;
  int j0 = t >> 6;
  int jstep = (gridDim.x*blockDim.x) >> 6;
  float af=0.f, ah=0.f;
  for (int j=j0; j<PER; j+=jstep){
    f16x2 v = HFin[(size_t)j*HDIM + m];
    ah += (float)v.x;
    af += (float)v.y;
  }
  __shared__ float red[256];
  red[threadIdx.x]=af; __syncthreads();
  if (threadIdx.x < 64) atomicAdd(&rootacc[m],    red[m]+red[64+m]+red[128+m]+red[192+m]);
  __syncthreads();
  red[threadIdx.x]=ah; __syncthreads();
  if (threadIdx.x < 64) atomicAdd(&rootacc[64+m], red[m]+red[64+m]+red[128+m]+red[192+m]);
}

__global__ void rootnode_kernel(
    const int* __restrict__ tok, const float* __restrict__ emb,
    const float* __restrict__ Wiou, const float* __restrict__ biou, const float* __restrict__ Uiou,
    const float* __restrict__ rootacc, float* __restrict__ out)
{
  int m = threadIdx.x;
  if (m >= HDIM) return;
  int t = tok[0];
  float ai=biou[m], ao=biou[HDIM+m], au=biou[2*HDIM+m];
  for (int e=0;e<EDIM;e++){
    float xe = emb[(size_t)t*EDIM+e];
    ai += Wiou[(size_t)m*EDIM+e]*xe;
    ao += Wiou[(size_t)(HDIM+m)*EDIM+e]*xe;
    au += Wiou[(size_t)(2*HDIM+m)*EDIM+e]*xe;
  }
  for (int k=0;k<HDIM;k++){
    float hv = rootacc[64+k];
    ai += Uiou[(size_t)m*HDIM+k]*hv;
    ao += Uiou[(size_t)(HDIM+m)*HDIM+k]*hv;
    au += Uiou[(size_t)(2*HDIM+m)*HDIM+k]*hv;
  }
  float c = sigf(ai)*tanh_f(au) + rootacc[m];
  out[m] = sigf(ao)*tanh_f(c);
}

// ================= launch =================
static inline char* alignup(char* p){
  uintptr_t u = (uintptr_t)p;
  u = (u + 255) & ~(uintptr_t)255;
  return (char*)u;
}

extern "C" void kernel_launch(void* const* d_in, const int* in_sizes, int n_in,
                              void* d_out, int out_size, void* d_ws, size_t ws_size,
                              hipStream_t stream)
{
  const int*   tok    = (const int*)d_in[0];
  const int*   parent = (const int*)d_in[1];
  const float* emb    = (const float*)d_in[4];
  const float* Wiou   = (const float*)d_in[5];
  const float* biou   = (const float*)d_in[6];
  const float* Uiou   = (const float*)d_in[7];
  const float* Wf     = (const float*)d_in[8];
  const float* bf     = (const float*)d_in[9];
  const float* Uf     = (const float*)d_in[10];
  float* out = (float*)d_out;

  char* w = (char*)d_ws;
  f16x2* HFA     = (f16x2*)w;  w = alignup(w + (size_t)PER*HDIM*sizeof(f16x2));
  f16x2* HFB     = (f16x2*)w;  w = alignup(w + (size_t)PER*HDIM*sizeof(f16x2));
  int*   cnt     = (int*)w;    w = alignup(w + (size_t)NN*sizeof(int));
  int*   off     = (int*)w;    w = alignup(w + (size_t)NN*sizeof(int));
  int*   cursor  = (int*)w;    w = alignup(w + (size_t)NN*sizeof(int));
  int*   childrow= (int*)w;    w = alignup(w + ((size_t)6*PER + 256)*sizeof(int));
  int*   bsum    = (int*)w;    w = alignup(w + 1024*sizeof(int));
  int*   bbase   = (int*)w;    w = alignup(w + 1024*sizeof(int));
  float* embWiou = (float*)w;  w = alignup(w + 1024*NIOU*sizeof(float));
  float* embWf   = (float*)w;  w = alignup(w + 1024*HDIM*sizeof(float));
  float* rootacc = (float*)w;  w = alignup(w + 128*sizeof(float));
  f16*   Ufpack  = (f16*)w;    w = alignup(w + 2*4*64*8*sizeof(f16));
  f16*   Biopack = (f16*)w;    w = alignup(w + 2*12*64*8*sizeof(f16));

  const int gALL = (6*PER + 255)/256;     // 3511

  hipMemsetAsync(cnt, 0, (size_t)(1 + 6*PER)*sizeof(int), stream);
  hipMemsetAsync(rootacc, 0, 128*sizeof(float), stream);

  countAll_kernel  <<<gALL, 256, 0, stream>>>(parent, cnt);
  scan1_kernel     <<<1024, 256, 0, stream>>>(cnt, bsum);
  scan2_kernel     <<<1, 1024, 0, stream>>>(bsum, bbase);
  scan3_kernel     <<<1024, 256, 0, stream>>>(cnt, bbase, off, cursor);
  scatterAll_kernel<<<gALL, 256, 0, stream>>>(parent, cursor, childrow);
  tablepack_kernel <<<1025, 256, 0, stream>>>(emb, Wiou, biou, Wf, bf, Uf, Uiou,
                                              embWiou, embWf, Ufpack, Biopack);

  // levels d=7 (leaves, no children) down to d=1 — node-order storage per level
  f16x2* bufs[2] = {HFA, HFB};
  int outIdx = 0;
  f16x2* last = HFA;
  for (int d=7; d>=1; --d){
    int poff = 1 + (d-1)*PER;
    f16x2* in  = bufs[1-outIdx];
    f16x2* ou  = bufs[outIdx];
    node_fused<<<(PER + 63)/64, 256, 0, stream>>>(tok, parent, off, childrow,
                                                  embWiou, embWf, Biopack, Ufpack,
                                                  in, ou, poff, (d==7) ? 1 : 0);
    last = ou;
    outIdx ^= 1;
  }

  // root: children are level-1 nodes, node order [0,PER)
  rootred_kernel<<<256, 256, 0, stream>>>(last, rootacc);
  rootnode_kernel<<<1, 64, 0, stream>>>(tok, emb, Wiou, biou, Uiou, rootacc, out);
}

// Round 12
// 546.634 us; speedup vs baseline: 1.0880x; 1.0128x over previous
//
#include <hip/hip_runtime.h>
#include <hip/hip_fp16.h>
#include <string.h>

#define PER  149796
#define NN   1048573          // 1 + 7*PER
#define HDIM 64
#define EDIM 32
#define NIOU 192

typedef _Float16 f16;
typedef _Float16 f16x8 __attribute__((ext_vector_type(8)));
typedef _Float16 f16x2 __attribute__((ext_vector_type(2)));
typedef float    f32x4 __attribute__((ext_vector_type(4)));

__device__ __forceinline__ float sigf(float x){ return 1.0f/(1.0f+__expf(-x)); }
__device__ __forceinline__ float tanh_f(float x){
  float ax = fabsf(x);
  float e  = __expf(-2.0f*ax);
  float t  = (1.0f - e)/(1.0f + e);
  return x < 0.0f ? -t : t;
}

// packed f16x2 global atomic add (fire-and-forget).
// Body only compiled on the device pass — the host pass just needs to parse
// an empty function (R11 failed because host pass lacked the atomicAdd overload).
__device__ __forceinline__ void atomAddH2(f16x2* p, f16 a, f16 b){
#if defined(__HIP_DEVICE_COMPILE__)
  typedef _Float16 h2 __attribute__((ext_vector_type(2)));
  h2 v; v[0]=a; v[1]=b;
  (void)__builtin_amdgcn_global_atomic_fadd_v2f16(
      (__attribute__((address_space(1))) h2*)p, v);
#else
  (void)p; (void)a; (void)b;
#endif
}

// ================= tables + MFMA packs (fused) =================
// B-frag order for mfma_f32_16x16x32_f16 (verified R4): lane L: n=t*16+(L&15), k=s*32+(L>>4)*8+j
__global__ __launch_bounds__(256) void tablepack_kernel(
    const float* __restrict__ emb, const float* __restrict__ Wiou, const float* __restrict__ biou,
    const float* __restrict__ Wf, const float* __restrict__ bf,
    const float* __restrict__ Uf, const float* __restrict__ Uiou,
    float* __restrict__ embWiou, float* __restrict__ embWf,
    f16* __restrict__ Bfp, f16* __restrict__ Biop)
{
  if (blockIdx.x < 1024){
    int v = blockIdx.x;
    int m = threadIdx.x;
    const float* x = emb + (size_t)v*EDIM;
    if (m < NIOU){
      float a = biou[m];
      #pragma unroll
      for (int e=0;e<EDIM;e++) a += Wiou[m*EDIM+e]*x[e];
      embWiou[(size_t)v*NIOU + m] = a;
    } else {
      int mm = m - NIOU;
      float a = bf[mm];
      #pragma unroll
      for (int e=0;e<EDIM;e++) a += Wf[mm*EDIM+e]*x[e];
      embWf[(size_t)v*HDIM + mm] = a;
    }
  } else {
    for (int i = threadIdx.x; i < 2*4*64*8; i += 256){
      int j = i & 7, L = (i>>3)&63, st = i>>9;
      int t = st & 3, s = st >> 2;
      int k = s*32 + (L>>4)*8 + j;
      int n = t*16 + (L&15);
      Bfp[i] = (f16)Uf[n*HDIM + k];
    }
    for (int i = threadIdx.x; i < 2*12*64*8; i += 256){
      int j = i & 7, L = (i>>3)&63, st = i>>9;
      int t = st % 12, s = st / 12;
      int k = s*32 + (L>>4)*8 + j;
      int n = t*16 + (L&15);
      Biop[i] = (f16)Uiou[n*HDIM + k];
    }
  }
}

// ================= per-level kernel (push design, no CSR) =================
// One wave per 16 nodes. mode: 0 = leaf (no accum read, atomic out)
//                             1 = mid  (accum read, atomic out)
//                             2 = level1 (accum read, plain contiguous out)
// accIn[j*64+lane] = {Σh, Σfc} of node j's children (f16x2), pre-accumulated.
// Output: {h, fc} pushed into parent's row of accOut via pk_add_f16 atomics.
__global__ __launch_bounds__(64,4) void level_kernel(
    const int* __restrict__ tok, const int* __restrict__ parent,
    const float* __restrict__ embWiou, const float* __restrict__ embWf,
    const f16* __restrict__ Biopack, const f16* __restrict__ Ufpack,
    const f16x2* __restrict__ accIn, f16x2* __restrict__ accOut,
    int poff, int ppoff, int mode)
{
  __shared__ f16 Ah[16*72];     // 2304 B
  __shared__ f16 FAf[16*68];    // 2176 B
  int lane = threadIdx.x;
  int j0   = blockIdx.x*16;
  int q = lane>>4, c16 = lane&15;

  // ---- phase 1: own accumulated child-sums (contiguous) -> LDS transpose
  if (mode != 0){
    #pragma unroll
    for (int i=0;i<16;i++){
      int j = j0 + i; if (j > PER-1) j = PER-1;
      f16x2 v = accIn[(size_t)j*HDIM + lane];
      Ah[i*72 + lane]  = v.x;
      FAf[i*68 + lane] = v.y;
    }
  } else {
    #pragma unroll
    for (int i=0;i<16;i++){
      Ah[i*72 + lane]  = (f16)0.f;
      FAf[i*68 + lane] = (f16)0.f;
    }
  }
  __syncthreads();
  f16x8 A0 = *(const f16x8*)(Ah + c16*72 + q*8);
  f16x8 A1 = *(const f16x8*)(Ah + c16*72 + 32 + q*8);

  // ---- phase 2: iou MFMA + epilogue
  const f16x8* Bp = (const f16x8*)Biopack;
  f32x4 acc[12];
  #pragma unroll
  for (int nt=0;nt<12;nt++) acc[nt] = (f32x4){0.f,0.f,0.f,0.f};
  #pragma unroll
  for (int nt=0;nt<12;nt++){
    f16x8 B0 = Bp[nt*64 + lane];
    f16x8 B1 = Bp[(12+nt)*64 + lane];
    acc[nt] = __builtin_amdgcn_mfma_f32_16x16x32_f16(A0, B0, acc[nt], 0,0,0);
    acc[nt] = __builtin_amdgcn_mfma_f32_16x16x32_f16(A1, B1, acc[nt], 0,0,0);
  }
  float cc[4][4];
  f16   hh[4][4];
  int   prow_[4]; int wt_[4]; bool ok_[4];
  #pragma unroll
  for (int r=0;r<4;r++){
    int j = j0 + q*4 + r;
    bool ok = j < PER;
    int jl = ok ? j : PER-1;
    int g = poff + jl;
    int tk = tok[g];
    const float* tr = embWiou + (size_t)tk*NIOU;
    ok_[r] = ok;
    if (mode != 2){
      int pg = parent[g];
      prow_[r] = pg - ppoff;          // parent's level-local row
      wt_[r]   = tok[pg];             // parent's token for Uf part
    } else {
      prow_[r] = jl;                  // own row (contiguous write)
      wt_[r]   = tok[0];              // root token
    }
    int prow = q*4 + r;
    #pragma unroll
    for (int nt=0;nt<4;nt++){
      int col = nt*16 + c16;
      float ai = acc[nt][r]   + tr[col];
      float ao = acc[nt+4][r] + tr[64+col];
      float au = acc[nt+8][r] + tr[128+col];
      float fav = (float)FAf[prow*68 + col];
      float c = sigf(ai)*tanh_f(au) + fav;
      float h = sigf(ao)*tanh_f(c);
      cc[r][nt] = c;
      hh[r][nt] = (f16)h;
    }
  }
  __syncthreads();
  // ---- phase 3: h -> Ah (A-layout), Uf MFMA, push {h,fc}
  #pragma unroll
  for (int r=0;r<4;r++)
    #pragma unroll
    for (int nt=0;nt<4;nt++)
      Ah[(q*4+r)*72 + nt*16 + c16] = hh[r][nt];
  __syncthreads();
  f16x8 H0 = *(const f16x8*)(Ah + c16*72 + q*8);
  f16x8 H1 = *(const f16x8*)(Ah + c16*72 + 32 + q*8);
  const f16x8* Up = (const f16x8*)Ufpack;
  f32x4 g4[4];
  #pragma unroll
  for (int nt=0;nt<4;nt++) g4[nt] = (f32x4){0.f,0.f,0.f,0.f};
  #pragma unroll
  for (int nt=0;nt<4;nt++){
    f16x8 B0 = Up[nt*64 + lane];
    f16x8 B1 = Up[(4+nt)*64 + lane];
    g4[nt] = __builtin_amdgcn_mfma_f32_16x16x32_f16(H0, B0, g4[nt], 0,0,0);
    g4[nt] = __builtin_amdgcn_mfma_f32_16x16x32_f16(H1, B1, g4[nt], 0,0,0);
  }
  #pragma unroll
  for (int r=0;r<4;r++){
    if (!ok_[r]) continue;
    const float* wr = embWf + (size_t)wt_[r]*HDIM;
    size_t rb = (size_t)prow_[r]*HDIM;
    #pragma unroll
    for (int nt=0;nt<4;nt++){
      int col = nt*16 + c16;
      float v = sigf(g4[nt][r] + wr[col]) * cc[r][nt];
      if (mode == 2){
        f16x2 o; o.x = hh[r][nt]; o.y = (f16)v;
        accOut[rb + col] = o;
      } else {
        atomAddH2(&accOut[rb + col], hh[r][nt], (f16)v);
      }
    }
  }
}

// ================= root =================
__global__ __launch_bounds__(256) void rootred_kernel(
    const f16x2* __restrict__ HFin, float* __restrict__ rootacc)
{
  int t = blockIdx.x*blockDim.x + threadIdx.x;
  int m = t & 63;
  int j0 = t >> 6;
  int jstep = (gridDim.x*blockDim.x) >> 6;
  float af=0.f, ah=0.f;
  for (int j=j0; j<PER; j+=jstep){
    f16x2 v = HFin[(size_t)j*HDIM + m];
    ah += (float)v.x;
    af += (float)v.y;
  }
  __shared__ float red[256];
  red[threadIdx.x]=af; __syncthreads();
  if (threadIdx.x < 64) atomicAdd(&rootacc[m],    red[m]+red[64+m]+red[128+m]+red[192+m]);
  __syncthreads();
  red[threadIdx.x]=ah; __syncthreads();
  if (threadIdx.x < 64) atomicAdd(&rootacc[64+m], red[m]+red[64+m]+red[128+m]+red[192+m]);
}

__global__ void rootnode_kernel(
    const int* __restrict__ tok, const float* __restrict__ emb,
    const float* __restrict__ Wiou, const float* __restrict__ biou, const float* __restrict__ Uiou,
    const float* __restrict__ rootacc, float* __restrict__ out)
{
  int m = threadIdx.x;
  if (m >= HDIM) return;
  int t = tok[0];
  float ai=biou[m], ao=biou[HDIM+m], au=biou[2*HDIM+m];
  for (int e=0;e<EDIM;e++){
    float xe = emb[(size_t)t*EDIM+e];
    ai += Wiou[(size_t)m*EDIM+e]*xe;
    ao += Wiou[(size_t)(HDIM+m)*EDIM+e]*xe;
    au += Wiou[(size_t)(2*HDIM+m)*EDIM+e]*xe;
  }
  for (int k=0;k<HDIM;k++){
    float hv = rootacc[64+k];
    ai += Uiou[(size_t)m*HDIM+k]*hv;
    ao += Uiou[(size_t)(HDIM+m)*HDIM+k]*hv;
    au += Uiou[(size_t)(2*HDIM+m)*HDIM+k]*hv;
  }
  float c = sigf(ai)*tanh_f(au) + rootacc[m];
  out[m] = sigf(ao)*tanh_f(c);
}

// ================= launch =================
static inline char* alignup(char* p){
  uintptr_t u = (uintptr_t)p;
  u = (u + 255) & ~(uintptr_t)255;
  return (char*)u;
}

extern "C" void kernel_launch(void* const* d_in, const int* in_sizes, int n_in,
                              void* d_out, int out_size, void* d_ws, size_t ws_size,
                              hipStream_t stream)
{
  const int*   tok    = (const int*)d_in[0];
  const int*   parent = (const int*)d_in[1];
  const float* emb    = (const float*)d_in[4];
  const float* Wiou   = (const float*)d_in[5];
  const float* biou   = (const float*)d_in[6];
  const float* Uiou   = (const float*)d_in[7];
  const float* Wf     = (const float*)d_in[8];
  const float* bf     = (const float*)d_in[9];
  const float* Uf     = (const float*)d_in[10];
  float* out = (float*)d_out;

  char* w = (char*)d_ws;
  size_t BUF = (size_t)PER*HDIM*sizeof(f16x2);     // 38.3 MB
  f16x2* bufA    = (f16x2*)w;  w = alignup(w + BUF);
  f16x2* bufB    = (f16x2*)w;  w = alignup(w + BUF);
  float* embWiou = (float*)w;  w = alignup(w + 1024*NIOU*sizeof(float));
  float* embWf   = (float*)w;  w = alignup(w + 1024*HDIM*sizeof(float));
  float* rootacc = (float*)w;  w = alignup(w + 128*sizeof(float));
  f16*   Ufpack  = (f16*)w;    w = alignup(w + 2*4*64*8*sizeof(f16));
  f16*   Biopack = (f16*)w;    w = alignup(w + 2*12*64*8*sizeof(f16));

  const int NB = (PER + 15)/16;   // 9363 blocks of 64 threads

  (void)hipMemsetAsync(rootacc, 0, 128*sizeof(float), stream);
  tablepack_kernel<<<1025, 256, 0, stream>>>(emb, Wiou, biou, Wf, bf, Uf, Uiou,
                                             embWiou, embWf, Ufpack, Biopack);

  // level d kernel: nodes at poff=1+(d-1)*PER; parents at ppoff=1+(d-2)*PER
  // d=7 (leaves): mode 0 -> atomic into bufA (accum for level 6)
  // d=6..2:       mode 1 -> read own accum, atomic into other buf
  // d=1:          mode 2 -> read own accum, plain write {h,fc} (for rootred)
  f16x2* accIn  = nullptr;
  f16x2* accOut = bufA;
  (void)hipMemsetAsync(bufA, 0, BUF, stream);
  level_kernel<<<NB, 64, 0, stream>>>(tok, parent, embWiou, embWf, Biopack, Ufpack,
                                      nullptr, bufA, 1 + 6*PER, 1 + 5*PER, 0);
  accIn = bufA; accOut = bufB;
  for (int d=6; d>=2; --d){
    (void)hipMemsetAsync(accOut, 0, BUF, stream);
    level_kernel<<<NB, 64, 0, stream>>>(tok, parent, embWiou, embWf, Biopack, Ufpack,
                                        accIn, accOut, 1 + (d-1)*PER, 1 + (d-2)*PER, 1);
    f16x2* t2 = accIn; accIn = accOut; accOut = t2;
  }
  // d=1: plain contiguous write into accOut (full overwrite, no memset)
  level_kernel<<<NB, 64, 0, stream>>>(tok, parent, embWiou, embWf, Biopack, Ufpack,
                                      accIn, accOut, 1, 0, 2);

  rootred_kernel<<<256, 256, 0, stream>>>(accOut, rootacc);
  rootnode_kernel<<<1, 64, 0, stream>>>(tok, emb, Wiou, biou, Uiou, rootacc, out);
}